// Round 1
// baseline (376.952 us; speedup 1.0000x reference)
//
#include <hip/hip_runtime.h>

#define BB 2
#define SS 2048
#define DD 1024
#define HH 16
#define DEPTH 64
#define MTOT (BB*SS)   // 4096

using f16 = _Float16;
typedef _Float16 f16x8 __attribute__((ext_vector_type(8)));
typedef _Float16 f16x4 __attribute__((ext_vector_type(4)));
typedef float f32x4 __attribute__((ext_vector_type(4)));

// ---------------- Projection GEMM: out = X @ W^T + b, fp32 in -> fp16 out ----------------
// mode 0: Q -> qh [b,h,s,d]   mode 1: K -> kh [b,h,s,d]   mode 2: V -> vt [b,h,d,s]
__global__ __launch_bounds__(256) void proj_kernel(
    const float* __restrict__ xq, const float* __restrict__ xk, const float* __restrict__ xv,
    const float* __restrict__ wq, const float* __restrict__ bq,
    const float* __restrict__ wk, const float* __restrict__ bk,
    const float* __restrict__ wv, const float* __restrict__ bv,
    f16* __restrict__ qh, f16* __restrict__ kh, f16* __restrict__ vt)
{
    const int mode = blockIdx.z;
    const float* X    = (mode==0) ? xq : (mode==1) ? xk : xv;
    const float* W    = (mode==0) ? wq : (mode==1) ? wk : wv;
    const float* bias = (mode==0) ? bq : (mode==1) ? bk : bv;

    __shared__ f16 As[128][72];   // 144B rows (16B-aligned, bank-conflict-free-ish)
    __shared__ f16 Bs[128][72];

    const int tid = threadIdx.x;
    const int wave = tid >> 6, lane = tid & 63;
    const int m0 = blockIdx.y * 128, n0 = blockIdx.x * 128;
    const int wm = (wave >> 1) * 64, wn = (wave & 1) * 64;
    const int lrow = lane & 15, lko = (lane >> 4) * 8;

    f32x4 acc[4][4] = {};

    for (int kk = 0; kk < DD; kk += 64) {
        __syncthreads();
        // stage A and B: 128x64 fp32 -> f16 (2048 float4 chunks each, 8 per thread)
        for (int i = 0; i < 8; ++i) {
            int c = tid + i * 256;
            int r = c >> 4, c4 = c & 15;
            f32x4 av = *(const f32x4*)(X + (size_t)(m0 + r) * DD + kk + c4 * 4);
            f32x4 bv4 = *(const f32x4*)(W + (size_t)(n0 + r) * DD + kk + c4 * 4);
            *(f16x4*)&As[r][c4 * 4] = (f16x4){(f16)av[0], (f16)av[1], (f16)av[2], (f16)av[3]};
            *(f16x4*)&Bs[r][c4 * 4] = (f16x4){(f16)bv4[0], (f16)bv4[1], (f16)bv4[2], (f16)bv4[3]};
        }
        __syncthreads();
        for (int kf = 0; kf < 2; ++kf) {
            f16x8 a[4], bf[4];
            for (int i = 0; i < 4; ++i) a[i]  = *(const f16x8*)&As[wm + i*16 + lrow][kf*32 + lko];
            for (int i = 0; i < 4; ++i) bf[i] = *(const f16x8*)&Bs[wn + i*16 + lrow][kf*32 + lko];
            for (int mi = 0; mi < 4; ++mi)
                for (int ni = 0; ni < 4; ++ni)
                    acc[mi][ni] = __builtin_amdgcn_mfma_f32_16x16x32_f16(a[mi], bf[ni], acc[mi][ni], 0, 0, 0);
        }
    }

    // epilogue: C frag layout col=lane&15, row=(lane>>4)*4+j  [verified m89]
    const int rbase = (lane >> 4) * 4;
    for (int ni = 0; ni < 4; ++ni) {
        int n = n0 + wn + ni * 16 + lrow;
        float bval = bias[n];
        int hh = n >> 6, dep = n & 63;
        for (int mi = 0; mi < 4; ++mi) {
            for (int j = 0; j < 4; ++j) {
                int m = m0 + wm + mi * 16 + rbase + j;
                int bb = m >> 11, s = m & 2047;
                float val = acc[mi][ni][j] + bval;
                if (mode == 2)
                    vt[((size_t)(bb * HH + hh) * DEPTH + dep) * SS + s] = (f16)val;
                else {
                    f16* dst = (mode == 0) ? qh : kh;
                    dst[((size_t)(bb * HH + hh) * SS + s) * DEPTH + dep] = (f16)val;
                }
            }
        }
    }
}

// ---------------- Attention: per (b,h), 64 q-rows per block, 4 waves x 16 rows ----------------
__global__ __launch_bounds__(256) void attn_kernel(
    const f16* __restrict__ qh, const f16* __restrict__ kh, const f16* __restrict__ vt,
    const float* __restrict__ mask, float* __restrict__ attn_out, f16* __restrict__ ctx)
{
    __shared__ float mlds[SS];        // mask bias per key, 8KB
    __shared__ f16 Kt[64][72];        // K tile [k-row][d]
    __shared__ f16 Vl[64][72];        // V tile [d-row][k]
    __shared__ f16 Pl[4][16][72];     // per-wave P tile [q][k]

    const int tid = threadIdx.x, wave = tid >> 6, lane = tid & 63;
    const int qb = blockIdx.x, bh = blockIdx.y;
    const int b = bh >> 4, h = bh & 15;
    const int q0 = qb * 64;
    const int lrow = lane & 15, lko = (lane >> 4) * 8;

    const f16* Qbase = qh + (size_t)bh * SS * DEPTH;
    const f16* Kbase = kh + (size_t)bh * SS * DEPTH;
    const f16* Vbase = vt + (size_t)bh * DEPTH * SS;

    for (int i = tid; i < SS; i += 256) mlds[i] = mask[b * SS + i] * -1e9f;

    // Q fragments held in registers for both passes
    f16x8 aq[2];
    for (int kf = 0; kf < 2; ++kf)
        aq[kf] = *(const f16x8*)(Qbase + (size_t)(q0 + wave * 16 + lrow) * DEPTH + kf * 32 + lko);

    float m_l[4], s_l[4];
    for (int j = 0; j < 4; ++j) { m_l[j] = -1e30f; s_l[j] = 0.f; }

    // ---- pass 1: online row max/sum (per-lane partials over this lane's columns) ----
    for (int kt = 0; kt < SS / 64; ++kt) {
        __syncthreads();
        for (int i = 0; i < 2; ++i) {
            int c = tid * 2 + i;
            int r = c >> 3, c8 = c & 7;
            *(f16x8*)&Kt[r][c8 * 8] = *(const f16x8*)(Kbase + (size_t)(kt * 64 + r) * DEPTH + c8 * 8);
        }
        __syncthreads();
        float lg[4][4];
        for (int nf = 0; nf < 4; ++nf) {
            f32x4 a4 = {};
            for (int kf = 0; kf < 2; ++kf) {
                f16x8 bf = *(const f16x8*)&Kt[nf * 16 + lrow][kf * 32 + lko];
                a4 = __builtin_amdgcn_mfma_f32_16x16x32_f16(aq[kf], bf, a4, 0, 0, 0);
            }
            float mb = mlds[kt * 64 + nf * 16 + lrow];
            for (int j = 0; j < 4; ++j) lg[nf][j] = a4[j] * 0.125f + mb;
        }
        for (int j = 0; j < 4; ++j) {
            float tmax = fmaxf(fmaxf(lg[0][j], lg[1][j]), fmaxf(lg[2][j], lg[3][j]));
            float nm = fmaxf(m_l[j], tmax);
            float ts = __expf(lg[0][j] - nm) + __expf(lg[1][j] - nm)
                     + __expf(lg[2][j] - nm) + __expf(lg[3][j] - nm);
            s_l[j] = s_l[j] * __expf(m_l[j] - nm) + ts;
            m_l[j] = nm;
        }
    }
    // merge the 16 per-lane partials within each column group
    for (int j = 0; j < 4; ++j) {
        float m = m_l[j], s = s_l[j];
        for (int off = 1; off < 16; off <<= 1) {
            float om = __shfl_xor(m, off);
            float os = __shfl_xor(s, off);
            float nm = fmaxf(m, om);
            s = s * __expf(m - nm) + os * __expf(om - nm);
            m = nm;
        }
        m_l[j] = m; s_l[j] = 1.0f / s;
    }

    // ---- pass 2: recompute logits, write normalized attn, accumulate PV ----
    f32x4 cacc[4] = {};
    float* arow = attn_out + ((size_t)bh * SS + q0 + wave * 16) * SS;
    for (int kt = 0; kt < SS / 64; ++kt) {
        __syncthreads();
        for (int i = 0; i < 2; ++i) {
            int c = tid * 2 + i;
            int r = c >> 3, c8 = c & 7;
            *(f16x8*)&Kt[r][c8 * 8] = *(const f16x8*)(Kbase + (size_t)(kt * 64 + r) * DEPTH + c8 * 8);
            *(f16x8*)&Vl[r][c8 * 8] = *(const f16x8*)(Vbase + (size_t)r * SS + kt * 64 + c8 * 8);
        }
        __syncthreads();
        for (int nf = 0; nf < 4; ++nf) {
            f32x4 a4 = {};
            for (int kf = 0; kf < 2; ++kf) {
                f16x8 bf = *(const f16x8*)&Kt[nf * 16 + lrow][kf * 32 + lko];
                a4 = __builtin_amdgcn_mfma_f32_16x16x32_f16(aq[kf], bf, a4, 0, 0, 0);
            }
            float mb = mlds[kt * 64 + nf * 16 + lrow];
            for (int j = 0; j < 4; ++j) {
                float p = __expf(a4[j] * 0.125f + mb - m_l[j]) * s_l[j];
                arow[(size_t)((lane >> 4) * 4 + j) * SS + kt * 64 + nf * 16 + lrow] = p;
                Pl[wave][(lane >> 4) * 4 + j][nf * 16 + lrow] = (f16)p;
            }
        }
        // PV: A = P (row=q, k contiguous), B = V (col=d, k contiguous) — same-wave LDS, no barrier
        for (int kf = 0; kf < 2; ++kf) {
            f16x8 pa = *(const f16x8*)&Pl[wave][lrow][kf * 32 + lko];
            for (int nf = 0; nf < 4; ++nf) {
                f16x8 bv = *(const f16x8*)&Vl[nf * 16 + lrow][kf * 32 + lko];
                cacc[nf] = __builtin_amdgcn_mfma_f32_16x16x32_f16(pa, bv, cacc[nf], 0, 0, 0);
            }
        }
    }
    // ctx [b, s, h, d] fp16 for dense GEMM
    for (int nf = 0; nf < 4; ++nf)
        for (int j = 0; j < 4; ++j) {
            int qrow = q0 + wave * 16 + (lane >> 4) * 4 + j;
            ctx[((size_t)(b * SS + qrow) * HH + h) * DEPTH + nf * 16 + lrow] = (f16)cacc[nf][j];
        }
}

// ---------------- Dense: out = ctx @ dense_w^T + b, fp16 A, fp32 W->f16, fp32 out ----------------
__global__ __launch_bounds__(256) void dense_kernel(
    const f16* __restrict__ ctx, const float* __restrict__ W,
    const float* __restrict__ bias, float* __restrict__ out)
{
    __shared__ f16 As[128][72];
    __shared__ f16 Bs[128][72];

    const int tid = threadIdx.x;
    const int wave = tid >> 6, lane = tid & 63;
    const int m0 = blockIdx.y * 128, n0 = blockIdx.x * 128;
    const int wm = (wave >> 1) * 64, wn = (wave & 1) * 64;
    const int lrow = lane & 15, lko = (lane >> 4) * 8;

    f32x4 acc[4][4] = {};

    for (int kk = 0; kk < DD; kk += 64) {
        __syncthreads();
        for (int i = 0; i < 4; ++i) {   // A: 1024 16B chunks
            int c = tid + i * 256;
            int r = c >> 3, c8 = c & 7;
            *(f16x8*)&As[r][c8 * 8] = *(const f16x8*)(ctx + (size_t)(m0 + r) * DD + kk + c8 * 8);
        }
        for (int i = 0; i < 8; ++i) {   // B: fp32 -> f16
            int c = tid + i * 256;
            int r = c >> 4, c4 = c & 15;
            f32x4 bv4 = *(const f32x4*)(W + (size_t)(n0 + r) * DD + kk + c4 * 4);
            *(f16x4*)&Bs[r][c4 * 4] = (f16x4){(f16)bv4[0], (f16)bv4[1], (f16)bv4[2], (f16)bv4[3]};
        }
        __syncthreads();
        for (int kf = 0; kf < 2; ++kf) {
            f16x8 a[4], bf[4];
            for (int i = 0; i < 4; ++i) a[i]  = *(const f16x8*)&As[wm + i*16 + lrow][kf*32 + lko];
            for (int i = 0; i < 4; ++i) bf[i] = *(const f16x8*)&Bs[wn + i*16 + lrow][kf*32 + lko];
            for (int mi = 0; mi < 4; ++mi)
                for (int ni = 0; ni < 4; ++ni)
                    acc[mi][ni] = __builtin_amdgcn_mfma_f32_16x16x32_f16(a[mi], bf[ni], acc[mi][ni], 0, 0, 0);
        }
    }

    const int rbase = (lane >> 4) * 4;
    for (int ni = 0; ni < 4; ++ni) {
        int n = n0 + wn + ni * 16 + lrow;
        float bval = bias[n];
        for (int mi = 0; mi < 4; ++mi)
            for (int j = 0; j < 4; ++j) {
                int m = m0 + wm + mi * 16 + rbase + j;
                out[(size_t)m * DD + n] = acc[mi][ni][j] + bval;
            }
    }
}

extern "C" void kernel_launch(void* const* d_in, const int* in_sizes, int n_in,
                              void* d_out, int out_size, void* d_ws, size_t ws_size,
                              hipStream_t stream) {
    const float* q       = (const float*)d_in[0];
    const float* k       = (const float*)d_in[1];
    const float* v       = (const float*)d_in[2];
    const float* mask    = (const float*)d_in[3];
    const float* wq_w    = (const float*)d_in[4];
    const float* wq_b    = (const float*)d_in[5];
    const float* wk_w    = (const float*)d_in[6];
    const float* wk_b    = (const float*)d_in[7];
    const float* wv_w    = (const float*)d_in[8];
    const float* wv_b    = (const float*)d_in[9];
    const float* dense_w = (const float*)d_in[10];
    const float* dense_b = (const float*)d_in[11];

    float* out  = (float*)d_out;
    float* attn = out + (size_t)MTOT * DD;          // output 1 region

    const size_t NPROJ = (size_t)BB * HH * SS * DEPTH;  // 4,194,304 elems
    f16* qh  = (f16*)d_ws;
    f16* kh  = qh + NPROJ;
    f16* vt  = kh + NPROJ;
    f16* ctx = vt + NPROJ;                          // total 32 MB of ws

    proj_kernel<<<dim3(8, 32, 3), 256, 0, stream>>>(q, k, v, wq_w, wq_b, wk_w, wk_b,
                                                    wv_w, wv_b, qh, kh, vt);
    attn_kernel<<<dim3(32, 32), 256, 0, stream>>>(qh, kh, vt, mask, attn, ctx);
    dense_kernel<<<dim3(8, 32), 256, 0, stream>>>(ctx, dense_w, dense_b, out);
}